// Round 10
// baseline (147164.966 us; speedup 1.0000x reference)
//
#include <hip/hip_runtime.h>
#include <hip/hip_bf16.h>
#include <math.h>

#define B 64
#define S 1024
#define D 1024
#define C 10
#define TD 3072  // 3*D

typedef __attribute__((ext_vector_type(8))) short s8v;   // 8 bf16 (A/B frag)
typedef __attribute__((ext_vector_type(4))) float f4v;   // 4 f32  (C/D frag)

__device__ __forceinline__ float wave_sum_bc(float v) {
    #pragma unroll
    for (int off = 1; off < 64; off <<= 1) v += __shfl_xor(v, off, 64);
    return v;
}
__device__ __forceinline__ float sigm(float x) { return 1.0f / (1.0f + expf(-x)); }
__device__ __forceinline__ short f2bf(float f) {
    __hip_bfloat16 h = __float2bfloat16(f);
    return *reinterpret_cast<short*>(&h);
}

// ---- same-XCD L2 communication primitives (sc0 = SE scope: bypass L1, hit L2) ----
__device__ __forceinline__ s8v sc0_load16(const short* p) {
    s8v r;
    asm volatile("global_load_dwordx4 %0, %1, off sc0" : "=v"(r) : "v"(p));
    return r;  // NOT valid until vm_drain()
}
__device__ __forceinline__ float sc0_load4_issue(const float* p) {
    float r;
    asm volatile("global_load_dword %0, %1, off sc0" : "=v"(r) : "v"(p));
    return r;  // NOT valid until vm_drain()
}
__device__ __forceinline__ unsigned sc0_poll_once(const unsigned* p) {
    unsigned r;
    asm volatile("global_load_dword %0, %1, off sc0\n\ts_waitcnt vmcnt(0)"
                 : "=v"(r) : "v"(p) : "memory");
    return r;
}
__device__ __forceinline__ void vm_drain() {
    asm volatile("s_waitcnt vmcnt(0)" ::: "memory");
    __builtin_amdgcn_sched_barrier(0);
}
__device__ __forceinline__ void l2_atomic_inc(unsigned* p) {
    unsigned one = 1u;
    asm volatile("global_atomic_add %0, %1, off" :: "v"(p), "v"(one) : "memory");
}

// ---------------------------------------------------------------------------
// k_pre: merged prologue (pooling partials + W packs + wscore). Unchanged math.
__global__ __launch_bounds__(256) void k_pre(const float* __restrict__ feat,
        const float* __restrict__ a_w, const float* __restrict__ W_ih,
        const float* __restrict__ W_hh, float* __restrict__ part, float* __restrict__ ml,
        short* __restrict__ BihP, short* __restrict__ BhhP, float* __restrict__ wscore) {
    __shared__ float sacc[4][1024];
    __shared__ float sml[4][2];
    int n = blockIdx.x, tid = threadIdx.x;

    if (n >= 1024) {
        if (n < 4096) {  // pack W -> bf16 B-fragments
            int rel = n - 1024;
            const float* Wsrc = (rel < 1536) ? W_ih : W_hh;
            short* dst = (rel < 1536) ? BihP : BhhP;
            int stride = (rel < 1536) ? (D + 1) : D;
            int rn = (rel < 1536) ? rel : rel - 1536;
            int gid = rn * 256 + tid;
            int fid = gid >> 6, l = gid & 63;
            int s = fid & 31, g = (fid >> 5) % 3, dt = fid / 96;
            int row = g * 1024 + dt * 16 + (l & 15);
            int k0 = s * 32 + ((l >> 4) << 3);
            const float* src = Wsrc + (size_t)row * stride + k0;
            short v[8];
            #pragma unroll
            for (int j = 0; j < 8; ++j) v[j] = f2bf(src[j]);
            short* d = dst + ((size_t)fid * 64 + l) * 8;
            #pragma unroll
            for (int j = 0; j < 8; ++j) d[j] = v[j];
        } else {  // wscore
            int j = (n - 4096) * 256 + tid;
            wscore[j] = W_ih[(size_t)j * (D + 1) + D];
        }
        return;
    }

    int ch = n & 15, b = n >> 4;
    int w = tid >> 6, lane = tid & 63;
    float4 aw[4], acc[4];
    #pragma unroll
    for (int r = 0; r < 4; ++r) {
        aw[r] = *reinterpret_cast<const float4*>(&a_w[r * 256 + lane * 4]);
        acc[r] = make_float4(0.f, 0.f, 0.f, 0.f);
    }
    float m = -INFINITY, l = 0.f;
    const float* fb = feat + ((size_t)b * S + ch * 64 + w * 16) * D;
    for (int i = 0; i < 16; ++i) {
        float4 f[4];
        #pragma unroll
        for (int r = 0; r < 4; ++r)
            f[r] = *reinterpret_cast<const float4*>(&fb[(size_t)i * D + r * 256 + lane * 4]);
        float dot = 0.f;
        #pragma unroll
        for (int r = 0; r < 4; ++r)
            dot += f[r].x * aw[r].x + f[r].y * aw[r].y + f[r].z * aw[r].z + f[r].w * aw[r].w;
        dot = wave_sum_bc(dot);
        if (dot <= m) {
            float wg = expf(dot - m);
            l += wg;
            #pragma unroll
            for (int r = 0; r < 4; ++r) {
                acc[r].x += wg * f[r].x; acc[r].y += wg * f[r].y;
                acc[r].z += wg * f[r].z; acc[r].w += wg * f[r].w;
            }
        } else {
            float sc = expf(m - dot);
            l = l * sc + 1.f;
            #pragma unroll
            for (int r = 0; r < 4; ++r) {
                acc[r].x = acc[r].x * sc + f[r].x; acc[r].y = acc[r].y * sc + f[r].y;
                acc[r].z = acc[r].z * sc + f[r].z; acc[r].w = acc[r].w * sc + f[r].w;
            }
            m = dot;
        }
    }
    #pragma unroll
    for (int r = 0; r < 4; ++r)
        *reinterpret_cast<float4*>(&sacc[w][r * 256 + lane * 4]) = acc[r];
    if (lane == 0) { sml[w][0] = m; sml[w][1] = l; }
    __syncthreads();
    float m0 = sml[0][0], m1 = sml[1][0], m2 = sml[2][0], m3 = sml[3][0];
    float mg = fmaxf(fmaxf(m0, m1), fmaxf(m2, m3));
    float s0 = expf(m0 - mg), s1 = expf(m1 - mg), s2 = expf(m2 - mg), s3 = expf(m3 - mg);
    int c = tid * 4;
    float4 a0 = *reinterpret_cast<float4*>(&sacc[0][c]);
    float4 a1 = *reinterpret_cast<float4*>(&sacc[1][c]);
    float4 a2 = *reinterpret_cast<float4*>(&sacc[2][c]);
    float4 a3 = *reinterpret_cast<float4*>(&sacc[3][c]);
    float4 o;
    o.x = s0 * a0.x + s1 * a1.x + s2 * a2.x + s3 * a3.x;
    o.y = s0 * a0.y + s1 * a1.y + s2 * a2.y + s3 * a3.y;
    o.z = s0 * a0.z + s1 * a1.z + s2 * a2.z + s3 * a3.z;
    o.w = s0 * a0.w + s1 * a1.w + s2 * a2.w + s3 * a3.w;
    *reinterpret_cast<float4*>(&part[((size_t)b * 16 + ch) * D + c]) = o;
    if (tid == 0) {
        float lg = s0 * sml[0][1] + s1 * sml[1][1] + s2 * sml[2][1] + s3 * sml[3][1];
        ml[(b * 16 + ch) * 2] = mg;
        ml[(b * 16 + ch) * 2 + 1] = lg;
    }
}

// ---------------------------------------------------------------------------
// k_mid: pool-combine -> pooledP A-fragments (8-batch chains, rows 8-15 zero)
// + chain counter reset (visibility via dispatch-boundary cache maintenance).
__global__ __launch_bounds__(256) void k_mid(const float* __restrict__ part,
        const float* __restrict__ ml, short* __restrict__ pooledP,
        unsigned* __restrict__ bar) {
    __shared__ float pl[1024];
    int b = blockIdx.x, tid = threadIdx.x;
    if (b == 0 && tid < 8) bar[tid * 64] = 0u;

    float mg = -INFINITY;
    #pragma unroll
    for (int q = 0; q < 16; ++q) mg = fmaxf(mg, ml[(b * 16 + q) * 2]);
    float denom = 0.f, sc[16];
    #pragma unroll
    for (int q = 0; q < 16; ++q) {
        sc[q] = expf(ml[(b * 16 + q) * 2] - mg);
        denom += sc[q] * ml[(b * 16 + q) * 2 + 1];
    }
    float inv = 1.f / denom;
    int cc = tid * 4;
    float4 o = make_float4(0.f, 0.f, 0.f, 0.f);
    #pragma unroll
    for (int q = 0; q < 16; ++q) {
        float4 p = *reinterpret_cast<const float4*>(&part[((size_t)b * 16 + q) * D + cc]);
        o.x += sc[q] * p.x; o.y += sc[q] * p.y; o.z += sc[q] * p.z; o.w += sc[q] * p.w;
    }
    pl[cc] = o.x * inv; pl[cc + 1] = o.y * inv; pl[cc + 2] = o.z * inv; pl[cc + 3] = o.w * inv;
    __syncthreads();

    // pack: chain c = b>>3, row r = b&7; zero row r+8.
    int c = b >> 3, r = b & 7;
    int s = tid >> 3, hi = (tid >> 1) & 3, z = tid & 1;
    int lane = (z ? (r + 8) : r) + hi * 16;
    short vals[8];
    #pragma unroll
    for (int j = 0; j < 8; ++j)
        vals[j] = z ? (short)0 : f2bf(pl[s * 32 + hi * 8 + j]);
    s8v* dst = reinterpret_cast<s8v*>(&pooledP[((size_t)(c * 32 + s) * 64 + lane) * 8]);
    s8v v8;
    #pragma unroll
    for (int j = 0; j < 8; ++j) v8[j] = vals[j];
    *dst = v8;
}

// ---------------------------------------------------------------------------
// k_persist: 10 GRU steps + outputs. 8 chains (8 batches each), chain c on
// XCD c (blocks bid%8==c, 32 blocks x 512 thr, 1/CU). Each block owns 32 d.
// Cross-block h/spart/counter all within one XCD's L2: plain stores,
// sc0 (SE-scope) loads, plain-L2 atomics. Bounded polls (no hang).
__global__ __launch_bounds__(512, 2) void k_persist(const s8v* __restrict__ BihP,
        const s8v* __restrict__ BhhP, const short* __restrict__ pooledP,
        short* hpA, short* hpB, const float* __restrict__ wscore,
        const float* __restrict__ b_ih, const float* __restrict__ b_hh,
        const float* __restrict__ W_out, const float* __restrict__ b_out,
        float* spart, float* __restrict__ out, unsigned* bar) {
    __shared__ float psum[8][16][2][49];
    __shared__ float gilds[8][3][33];
    __shared__ float hl[8][33];
    __shared__ float sredS[8][33];
    __shared__ float sredO[8][33];
    __shared__ unsigned short hbf[16][32];

    int tid = threadIdx.x, w = tid >> 6, l = tid & 63;
    int bid = blockIdx.x, c = bid & 7, idx = bid >> 3;  // chain c on XCD c
    bool epi = (tid < 256);
    int eb = tid >> 5;       // batch-row 0..7 (epi threads)
    int ec = tid & 31;       // d-col 0..31 / reduce index
    int d = idx * 32 + ec;
    unsigned* cnt = &bar[c * 64];

    if (tid >= 256) {  // zero A-tile rows 8..15 once
        hbf[8 + ((tid - 256) >> 5)][(tid - 256) & 31] = 0;
    }

    float e_bo = b_out[0];
    float e_b0 = 0.f, e_b1 = 0.f, e_b2 = 0.f, e_wo = 0.f;
    float e_w0 = 0.f, e_w1 = 0.f, e_w2 = 0.f, e_i0 = 0.f, e_i1 = 0.f, e_i2 = 0.f;
    if (epi) {
        e_b0 = b_hh[d]; e_b1 = b_hh[D + d]; e_b2 = b_hh[2 * D + d];
        e_wo = W_out[d];
        e_w0 = wscore[d]; e_w1 = wscore[D + d]; e_w2 = wscore[2 * D + d];
        e_i0 = b_ih[d]; e_i1 = b_ih[D + d]; e_i2 = b_ih[2 * D + d];
    }

    // ---- step 0: A = pooledP (boundary-flushed, plain loads), B = W_ih ----
    {
        f4v acc[2][3];
        #pragma unroll
        for (int ct = 0; ct < 2; ++ct)
            #pragma unroll
            for (int g = 0; g < 3; ++g) acc[ct][g] = (f4v){0.f, 0.f, 0.f, 0.f};
        #pragma unroll
        for (int s8 = 0; s8 < 4; ++s8) {
            int s = w * 4 + s8;
            s8v a = *reinterpret_cast<const s8v*>(&pooledP[((size_t)(c * 32 + s) * 64 + l) * 8]);
            #pragma unroll
            for (int ct = 0; ct < 2; ++ct)
                #pragma unroll
                for (int g = 0; g < 3; ++g) {
                    s8v bb = BihP[((size_t)((2 * idx + ct) * 3 + g) * 32 + s) * 64 + l];
                    acc[ct][g] = __builtin_amdgcn_mfma_f32_16x16x32_bf16(a, bb, acc[ct][g], 0, 0, 0);
                }
        }
        #pragma unroll
        for (int ct = 0; ct < 2; ++ct)
            #pragma unroll
            for (int g = 0; g < 3; ++g)
                #pragma unroll
                for (int r = 0; r < 4; ++r)
                    psum[w][(l >> 4) * 4 + r][ct][g * 16 + (l & 15)] = acc[ct][g][r];
        __syncthreads();
        if (epi) {
            int ct = ec >> 4, c16 = ec & 15;
            float g3[3];
            #pragma unroll
            for (int g = 0; g < 3; ++g) {
                float v = 0.f;
                #pragma unroll
                for (int ww = 0; ww < 8; ++ww) v += psum[ww][eb][ct][g * 16 + c16];
                g3[g] = v;
            }
            float gir = g3[0] + e_i0, giz = g3[1] + e_i1, gin = g3[2] + e_i2;
            gilds[eb][0][ec] = gir; gilds[eb][1][ec] = giz; gilds[eb][2][ec] = gin;
            float rr = sigm(gir + e_b0);
            float zz = sigm(giz + e_b1);
            float nn = tanhf(gin + rr * e_b2);
            float hnew = (1.f - zz) * nn;  // h0 = 0
            hl[eb][ec] = hnew;
            hbf[eb][ec] = (unsigned short)f2bf(hnew);
            sredO[eb][ec] = hnew * e_wo;
        }
        __syncthreads();
        if (tid < 64) {
            s8v hv;
            #pragma unroll
            for (int j = 0; j < 8; ++j) hv[j] = (short)hbf[l & 15][((l >> 4) << 3) + j];
            *reinterpret_cast<s8v*>(&hpA[((size_t)(c * 32 + idx) * 64 + l) * 8]) = hv;
            if (tid < 8) {
                float v = 0.f;
                #pragma unroll
                for (int q = 0; q < 32; ++q) v += sredO[tid][q];
                spart[(((size_t)0 * 8 + c) * 8 + tid) * 32 + idx] = v;
            }
            vm_drain();
            if (tid == 0) l2_atomic_inc(cnt);
        }
    }

    // ---- W_hh B-fragments -> registers (latency hides under step-0 tail) ----
    s8v Bw[4][2][3];
    #pragma unroll
    for (int s8 = 0; s8 < 4; ++s8) {
        int s = w * 4 + s8;
        #pragma unroll
        for (int ct = 0; ct < 2; ++ct)
            #pragma unroll
            for (int g = 0; g < 3; ++g)
                Bw[s8][ct][g] = BhhP[((size_t)((2 * idx + ct) * 3 + g) * 32 + s) * 64 + l];
    }

    // ---- steps 1..9 ----
    for (int t = 1; t < C; ++t) {
        if (tid == 0) {  // bounded poll: same-XCD L2 read of chain counter
            unsigned tgt = 32u * (unsigned)t;
            int it = 0;
            while (sc0_poll_once(cnt) < tgt && ++it < (1 << 17))
                __builtin_amdgcn_s_sleep(2);
        }
        __syncthreads();
        const short* hin = (t & 1) ? hpA : hpB;
        short* hout = (t & 1) ? hpB : hpA;
        float spv = 0.f;
        if (epi) spv = sc0_load4_issue(&spart[(((size_t)(t - 1) * 8 + c) * 8 + eb) * 32 + ec]);
        s8v a[4];
        #pragma unroll
        for (int s8 = 0; s8 < 4; ++s8) {
            int s = w * 4 + s8;
            a[s8] = sc0_load16(&hin[((size_t)(c * 32 + s) * 64 + l) * 8]);
        }
        vm_drain();
        if (epi) sredS[eb][ec] = spv;
        f4v acc[2][3];
        #pragma unroll
        for (int ct = 0; ct < 2; ++ct)
            #pragma unroll
            for (int g = 0; g < 3; ++g) acc[ct][g] = (f4v){0.f, 0.f, 0.f, 0.f};
        #pragma unroll
        for (int s8 = 0; s8 < 4; ++s8)
            #pragma unroll
            for (int ct = 0; ct < 2; ++ct)
                #pragma unroll
                for (int g = 0; g < 3; ++g)
                    acc[ct][g] = __builtin_amdgcn_mfma_f32_16x16x32_bf16(a[s8], Bw[s8][ct][g],
                                                                         acc[ct][g], 0, 0, 0);
        #pragma unroll
        for (int ct = 0; ct < 2; ++ct)
            #pragma unroll
            for (int g = 0; g < 3; ++g)
                #pragma unroll
                for (int r = 0; r < 4; ++r)
                    psum[w][(l >> 4) * 4 + r][ct][g * 16 + (l & 15)] = acc[ct][g][r];
        __syncthreads();
        if (epi) {
            int ct = ec >> 4, c16 = ec & 15;
            float g3[3];
            #pragma unroll
            for (int g = 0; g < 3; ++g) {
                float v = 0.f;
                #pragma unroll
                for (int ww = 0; ww < 8; ++ww) v += psum[ww][eb][ct][g * 16 + c16];
                g3[g] = v;
            }
            float ssum = e_bo;
            #pragma unroll
            for (int q = 0; q < 32; ++q) ssum += sredS[eb][q];
            float score = sigm(ssum);
            float gir = gilds[eb][0][ec] + score * e_w0;
            float giz = gilds[eb][1][ec] + score * e_w1;
            float gin = gilds[eb][2][ec] + score * e_w2;
            float rr = sigm(gir + e_b0 + g3[0]);
            float zz = sigm(giz + e_b1 + g3[1]);
            float nn = tanhf(gin + rr * (e_b2 + g3[2]));
            float hnew = (1.f - zz) * nn + zz * hl[eb][ec];
            hl[eb][ec] = hnew;
            hbf[eb][ec] = (unsigned short)f2bf(hnew);
            sredO[eb][ec] = hnew * e_wo;
        }
        __syncthreads();
        if (tid < 64) {
            s8v hv;
            #pragma unroll
            for (int j = 0; j < 8; ++j) hv[j] = (short)hbf[l & 15][((l >> 4) << 3) + j];
            *reinterpret_cast<s8v*>(&hout[((size_t)(c * 32 + idx) * 64 + l) * 8]) = hv;
            if (tid < 8) {
                float v = 0.f;
                #pragma unroll
                for (int q = 0; q < 32; ++q) v += sredO[tid][q];
                spart[(((size_t)t * 8 + c) * 8 + tid) * 32 + idx] = v;
                if (idx == 0) {  // score_t-1 = this step's input score
                    float ssum2 = e_bo;
                    #pragma unroll
                    for (int q = 0; q < 32; ++q) ssum2 += sredS[tid][q];
                    out[(8 * c + tid) * C + (t - 1)] = sigm(ssum2);
                }
            }
            vm_drain();
            if (tid == 0) l2_atomic_inc(cnt);
        }
    }

    // ---- tail: out[:, C-1] by idx==0 block of each chain ----
    if (idx == 0) {
        if (tid == 0) {
            unsigned tgt = 32u * (unsigned)C;
            int it = 0;
            while (sc0_poll_once(cnt) < tgt && ++it < (1 << 17))
                __builtin_amdgcn_s_sleep(2);
        }
        __syncthreads();
        float spv = 0.f;
        if (epi) spv = sc0_load4_issue(&spart[(((size_t)(C - 1) * 8 + c) * 8 + eb) * 32 + ec]);
        vm_drain();
        if (epi) sredS[eb][ec] = spv;
        __syncthreads();
        if (tid < 8) {
            float ssum = e_bo;
            #pragma unroll
            for (int q = 0; q < 32; ++q) ssum += sredS[tid][q];
            out[(8 * c + tid) * C + (C - 1)] = sigm(ssum);
        }
    }
}

extern "C" void kernel_launch(void* const* d_in, const int* in_sizes, int n_in,
                              void* d_out, int out_size, void* d_ws, size_t ws_size,
                              hipStream_t stream) {
    const float* feat  = (const float*)d_in[0];
    const float* a_w   = (const float*)d_in[1];
    const float* W_ih  = (const float*)d_in[2];
    const float* W_hh  = (const float*)d_in[3];
    const float* b_ih  = (const float*)d_in[4];
    const float* b_hh  = (const float*)d_in[5];
    const float* W_out = (const float*)d_in[6];
    const float* b_out = (const float*)d_in[7];
    float* out = (float*)d_out;
    float* ws = (float*)d_ws;

    float* part    = ws;                            // B*16*D f      = 1,048,576
    float* ml      = part + (size_t)B * 16 * D;     // B*16*2 f
    float* spart   = ml + B * 16 * 2;               // C*8*8*32 f    = 20,480
    float* wscore  = spart + (size_t)C * 8 * 8 * 32;// TD f
    short* pooledP = (short*)(wscore + TD);         // 8*32*64*8 sh  = 131,072
    short* hpA     = pooledP + (size_t)8 * 32 * 64 * 8;
    short* hpB     = hpA + (size_t)8 * 32 * 64 * 8;
    short* BihP    = hpB + (size_t)8 * 32 * 64 * 8; // D*TD sh
    short* BhhP    = BihP + (size_t)D * TD;         // D*TD sh
    unsigned* bar  = (unsigned*)(BhhP + (size_t)D * TD);  // 8*64 u32

    k_pre<<<dim3(4108), 256, 0, stream>>>(feat, a_w, W_ih, W_hh, part, ml,
                                          BihP, BhhP, wscore);
    k_mid<<<dim3(64), 256, 0, stream>>>(part, ml, pooledP, bar);
    k_persist<<<dim3(256), 512, 0, stream>>>((const s8v*)BihP, (const s8v*)BhhP,
                                             pooledP, hpA, hpB, wscore, b_ih, b_hh,
                                             W_out, b_out, spart, out, bar);
}

// Round 11
// 112.710 us; speedup vs baseline: 1305.6948x; 1305.6948x over previous
//
#include <hip/hip_runtime.h>
#include <hip/hip_bf16.h>
#include <math.h>

#define B 64
#define S 1024
#define D 1024
#define C 10
#define TD 3072  // 3*D

typedef __attribute__((ext_vector_type(8))) short s8v;   // 8 bf16 (A/B frag)
typedef __attribute__((ext_vector_type(4))) float f4v;   // 4 f32  (C/D frag)
typedef unsigned long long u64;

__device__ __forceinline__ float wave_sum_bc(float v) {
    #pragma unroll
    for (int off = 1; off < 64; off <<= 1) v += __shfl_xor(v, off, 64);
    return v;
}
__device__ __forceinline__ float sigm(float x) { return 1.0f / (1.0f + expf(-x)); }
__device__ __forceinline__ short f2bf(float f) {
    __hip_bfloat16 h = __float2bfloat16(f);
    return *reinterpret_cast<short*>(&h);
}
// Agent-scope relaxed atomics: routed to L3 coherence point, no L2 staleness.
__device__ __forceinline__ u64 aload64(u64* p) {
    return __hip_atomic_load(p, __ATOMIC_RELAXED, __HIP_MEMORY_SCOPE_AGENT);
}
__device__ __forceinline__ void astore64(u64* p, u64 v) {
    __hip_atomic_store(p, v, __ATOMIC_RELAXED, __HIP_MEMORY_SCOPE_AGENT);
}
__device__ __forceinline__ void astoref(float* p, float v) {
    __hip_atomic_store(p, v, __ATOMIC_RELAXED, __HIP_MEMORY_SCOPE_AGENT);
}
__device__ __forceinline__ void astoreu(unsigned* p, unsigned v) {
    __hip_atomic_store(p, v, __ATOMIC_RELAXED, __HIP_MEMORY_SCOPE_AGENT);
}
__device__ __forceinline__ unsigned aloadu(unsigned* p) {
    return __hip_atomic_load(p, __ATOMIC_RELAXED, __HIP_MEMORY_SCOPE_AGENT);
}
// Wave-parallel flag wait: lanes [0,nf) poll one flag each; no RMW anywhere.
__device__ __forceinline__ void flag_wait(unsigned* flags, int nf, unsigned tgt, int l) {
    unsigned v = 0xffffffffu;
    for (;;) {
        if (l < nf) v = aloadu(&flags[l]);
        if (__all(v >= tgt)) break;
        __builtin_amdgcn_s_sleep(2);
    }
    asm volatile("" ::: "memory");  // keep data loads after the poll
}

// ---------------------------------------------------------------------------
// k_pre: merged prologue (pooling partials + W packs + wscore + flag zero).
__global__ __launch_bounds__(256) void k_pre(const float* __restrict__ feat,
        const float* __restrict__ a_w, const float* __restrict__ W_ih,
        const float* __restrict__ W_hh, float* __restrict__ part, float* __restrict__ ml,
        short* __restrict__ BihP, short* __restrict__ BhhP, float* __restrict__ wscore,
        unsigned* __restrict__ bar) {
    __shared__ float sacc[4][1024];
    __shared__ float sml[4][2];
    int n = blockIdx.x, tid = threadIdx.x;

    if (n >= 1024) {
        if (n < 4096) {  // pack W -> bf16 B-fragments
            int rel = n - 1024;
            const float* Wsrc = (rel < 1536) ? W_ih : W_hh;
            short* dst = (rel < 1536) ? BihP : BhhP;
            int stride = (rel < 1536) ? (D + 1) : D;
            int rn = (rel < 1536) ? rel : rel - 1536;
            int gid = rn * 256 + tid;
            int fid = gid >> 6, l = gid & 63;
            int s = fid & 31, g = (fid >> 5) % 3, dt = fid / 96;
            int row = g * 1024 + dt * 16 + (l & 15);
            int k0 = s * 32 + ((l >> 4) << 3);
            const float* src = Wsrc + (size_t)row * stride + k0;
            short v[8];
            #pragma unroll
            for (int j = 0; j < 8; ++j) v[j] = f2bf(src[j]);
            short* d = dst + ((size_t)fid * 64 + l) * 8;
            #pragma unroll
            for (int j = 0; j < 8; ++j) d[j] = v[j];
        } else {  // wscore + flag zero
            int j = (n - 4096) * 256 + tid;
            wscore[j] = W_ih[(size_t)j * (D + 1) + D];
            if (n == 4096) {
                bar[tid] = 0u;                       // step flags [0,256)
                if (tid < 64) bar[256 + tid] = 0u;   // pool flags [256,320)
            }
        }
        return;
    }

    int ch = n & 15, b = n >> 4;
    int w = tid >> 6, lane = tid & 63;
    float4 aw[4], acc[4];
    #pragma unroll
    for (int r = 0; r < 4; ++r) {
        aw[r] = *reinterpret_cast<const float4*>(&a_w[r * 256 + lane * 4]);
        acc[r] = make_float4(0.f, 0.f, 0.f, 0.f);
    }
    float m = -INFINITY, l = 0.f;
    const float* fb = feat + ((size_t)b * S + ch * 64 + w * 16) * D;
    for (int i = 0; i < 16; ++i) {
        float4 f[4];
        #pragma unroll
        for (int r = 0; r < 4; ++r)
            f[r] = *reinterpret_cast<const float4*>(&fb[(size_t)i * D + r * 256 + lane * 4]);
        float dot = 0.f;
        #pragma unroll
        for (int r = 0; r < 4; ++r)
            dot += f[r].x * aw[r].x + f[r].y * aw[r].y + f[r].z * aw[r].z + f[r].w * aw[r].w;
        dot = wave_sum_bc(dot);
        if (dot <= m) {
            float wg = expf(dot - m);
            l += wg;
            #pragma unroll
            for (int r = 0; r < 4; ++r) {
                acc[r].x += wg * f[r].x; acc[r].y += wg * f[r].y;
                acc[r].z += wg * f[r].z; acc[r].w += wg * f[r].w;
            }
        } else {
            float sc = expf(m - dot);
            l = l * sc + 1.f;
            #pragma unroll
            for (int r = 0; r < 4; ++r) {
                acc[r].x = acc[r].x * sc + f[r].x; acc[r].y = acc[r].y * sc + f[r].y;
                acc[r].z = acc[r].z * sc + f[r].z; acc[r].w = acc[r].w * sc + f[r].w;
            }
            m = dot;
        }
    }
    #pragma unroll
    for (int r = 0; r < 4; ++r)
        *reinterpret_cast<float4*>(&sacc[w][r * 256 + lane * 4]) = acc[r];
    if (lane == 0) { sml[w][0] = m; sml[w][1] = l; }
    __syncthreads();
    float m0 = sml[0][0], m1 = sml[1][0], m2 = sml[2][0], m3 = sml[3][0];
    float mg = fmaxf(fmaxf(m0, m1), fmaxf(m2, m3));
    float s0 = expf(m0 - mg), s1 = expf(m1 - mg), s2 = expf(m2 - mg), s3 = expf(m3 - mg);
    int c = tid * 4;
    float4 a0 = *reinterpret_cast<float4*>(&sacc[0][c]);
    float4 a1 = *reinterpret_cast<float4*>(&sacc[1][c]);
    float4 a2 = *reinterpret_cast<float4*>(&sacc[2][c]);
    float4 a3 = *reinterpret_cast<float4*>(&sacc[3][c]);
    float4 o;
    o.x = s0 * a0.x + s1 * a1.x + s2 * a2.x + s3 * a3.x;
    o.y = s0 * a0.y + s1 * a1.y + s2 * a2.y + s3 * a3.y;
    o.z = s0 * a0.z + s1 * a1.z + s2 * a2.z + s3 * a3.z;
    o.w = s0 * a0.w + s1 * a1.w + s2 * a2.w + s3 * a3.w;
    *reinterpret_cast<float4*>(&part[((size_t)b * 16 + ch) * D + c]) = o;
    if (tid == 0) {
        float lg = s0 * sml[0][1] + s1 * sml[1][1] + s2 * sml[2][1] + s3 * sml[3][1];
        ml[(b * 16 + ch) * 2] = mg;
        ml[(b * 16 + ch) * 2 + 1] = lg;
    }
}

// ---------------------------------------------------------------------------
// k_persist: pool-combine + step0 + 9 GRU steps + final.
// Grid 256 = (dt 0..63)x(bh 0..3), block 512 = 8 waves (k-eighths).
// Sync: per-producer generation flags (bar[bh*64+dt] = t+1), no atomics/RMW.
// Cross-block data via agent-scope relaxed (L3-coherent) loads/stores.
__global__ __launch_bounds__(512, 2) void k_persist(const s8v* __restrict__ BihP,
        const s8v* __restrict__ BhhP, short* pooledP,
        u64* hpA, u64* hpB, const float* __restrict__ wscore,
        const float* __restrict__ b_ih, const float* __restrict__ b_hh,
        const float* __restrict__ W_out, const float* __restrict__ b_out,
        const float* __restrict__ part, const float* __restrict__ ml,
        float* spart, float* __restrict__ out, unsigned* bar) {
    __shared__ float psum[8][16][49];
    __shared__ float gilds[16][49];
    __shared__ float hl[16][17];
    __shared__ float sredS2[16][33];
    __shared__ float sredO[16][17];
    __shared__ unsigned short hbf[16][16];

    int tid = threadIdx.x, w = tid >> 6, l = tid & 63;
    int n = blockIdx.x, xcd = n & 7, slot = n >> 3;
    int dt = xcd * 8 + (slot & 7), bh = slot >> 3;
    int bq0 = bh * 16;
    int lb = tid & 15, c = (tid >> 4) & 15, c8 = tid >> 4;  // c8 0..31
    bool epi = (tid < 256);
    int b = bq0 + lb, d = dt * 16 + c;
    unsigned* stepflags = &bar[bh * 64];   // 64 per chain
    unsigned* poolflags = &bar[256];       // 64
    u64* poolU = (u64*)pooledP;

    // ---- Phase A: pool-combine (blocks 0..63), u64 agent stores + flag ----
    if (n < 64 && tid < 256) {
        int bb = n;
        float mg = -INFINITY;
        #pragma unroll
        for (int q = 0; q < 16; ++q) mg = fmaxf(mg, ml[(bb * 16 + q) * 2]);
        float denom = 0.f, sc[16];
        #pragma unroll
        for (int q = 0; q < 16; ++q) {
            sc[q] = expf(ml[(bb * 16 + q) * 2] - mg);
            denom += sc[q] * ml[(bb * 16 + q) * 2 + 1];
        }
        float inv = 1.f / denom;
        int cc = tid * 4;
        float4 o = make_float4(0.f, 0.f, 0.f, 0.f);
        #pragma unroll
        for (int q = 0; q < 16; ++q) {
            float4 p = *reinterpret_cast<const float4*>(&part[((size_t)bb * 16 + q) * D + cc]);
            o.x += sc[q] * p.x; o.y += sc[q] * p.y; o.z += sc[q] * p.z; o.w += sc[q] * p.w;
        }
        u64 v = (u64)(unsigned short)f2bf(o.x * inv) |
                ((u64)(unsigned short)f2bf(o.y * inv) << 16) |
                ((u64)(unsigned short)f2bf(o.z * inv) << 32) |
                ((u64)(unsigned short)f2bf(o.w * inv) << 48);
        int lane2 = (bb & 15) + (((cc >> 3) & 3) << 4);
        size_t idx = (((size_t)(bb >> 4) * 32 + (cc >> 5)) * 64 + lane2) * 2 + ((cc >> 2) & 1);
        astore64(&poolU[idx], v);
    }
    if (n < 64) {
        __syncthreads();
        if (tid == 0) {
            asm volatile("s_waitcnt vmcnt(0)" ::: "memory");
            astoreu(&poolflags[n], 1u);
        }
    }

    // ---- Preload constants + W_hh fragments (overlaps pool wait) ----
    float e_bo = b_out[0];
    float e_b0 = 0.f, e_b1 = 0.f, e_b2 = 0.f, e_wo = 0.f;
    float e_w0 = 0.f, e_w1 = 0.f, e_w2 = 0.f, e_i0 = 0.f, e_i1 = 0.f, e_i2 = 0.f;
    if (epi) {
        e_b0 = b_hh[d]; e_b1 = b_hh[D + d]; e_b2 = b_hh[2 * D + d];
        e_wo = W_out[d];
        e_w0 = wscore[d]; e_w1 = wscore[D + d]; e_w2 = wscore[2 * D + d];
        e_i0 = b_ih[d]; e_i1 = b_ih[D + d]; e_i2 = b_ih[2 * D + d];
    }
    s8v Bw[4][3];
    #pragma unroll
    for (int s8 = 0; s8 < 4; ++s8) {
        int s = w * 4 + s8;
        #pragma unroll
        for (int g = 0; g < 3; ++g)
            Bw[s8][g] = BhhP[((size_t)(dt * 3 + g) * 32 + s) * 64 + l];
    }

    // ---- wait for pooled (wave 0 polls 64 flags in parallel) ----
    if (w == 0) flag_wait(poolflags, 64, 1u, l);
    __syncthreads();

    // ---- step 0: A = pooledP (aload64), B = W_ih ----
    {
        f4v acc[3];
        #pragma unroll
        for (int g = 0; g < 3; ++g) acc[g] = (f4v){0.f, 0.f, 0.f, 0.f};
        #pragma unroll
        for (int s8 = 0; s8 < 4; ++s8) {
            int s = w * 4 + s8;
            size_t base = (((size_t)bh * 32 + s) * 64 + l) * 2;
            union { u64 q[2]; s8v v; } au;
            au.q[0] = aload64(&poolU[base]);
            au.q[1] = aload64(&poolU[base + 1]);
            #pragma unroll
            for (int g = 0; g < 3; ++g) {
                s8v bb2 = BihP[((size_t)(dt * 3 + g) * 32 + s) * 64 + l];
                acc[g] = __builtin_amdgcn_mfma_f32_16x16x32_bf16(au.v, bb2, acc[g], 0, 0, 0);
            }
        }
        #pragma unroll
        for (int g = 0; g < 3; ++g)
            #pragma unroll
            for (int r = 0; r < 4; ++r)
                psum[w][(l >> 4) * 4 + r][g * 16 + (l & 15)] = acc[g][r];
        __syncthreads();
        if (epi) {
            float g3[3];
            #pragma unroll
            for (int g = 0; g < 3; ++g) {
                float v = 0.f;
                #pragma unroll
                for (int ww = 0; ww < 8; ++ww) v += psum[ww][lb][g * 16 + c];
                g3[g] = v;
            }
            float gir = g3[0] + e_i0, giz = g3[1] + e_i1, gin = g3[2] + e_i2;
            gilds[lb][c] = gir; gilds[lb][16 + c] = giz; gilds[lb][32 + c] = gin;
            float rr = sigm(gir + e_b0);
            float zz = sigm(giz + e_b1);
            float nn = tanhf(gin + rr * e_b2);
            float hnew = (1.f - zz) * nn;  // hprev = 0
            hl[lb][c] = hnew;
            hbf[lb][c] = (unsigned short)f2bf(hnew);
            sredO[lb][c] = hnew * e_wo;
        }
        __syncthreads();
        if (tid < 64) {
            int lb2 = tid & 15, k4 = tid >> 4;
            u64 v = (u64)hbf[lb2][k4 * 4] | ((u64)hbf[lb2][k4 * 4 + 1] << 16) |
                    ((u64)hbf[lb2][k4 * 4 + 2] << 32) | ((u64)hbf[lb2][k4 * 4 + 3] << 48);
            int q2 = (2 * dt + (k4 >> 1)) & 3;
            int lane2 = lb2 + (q2 << 4);
            astore64(&hpA[(((size_t)bh * 32 + (dt >> 1)) * 64 + lane2) * 2 + (k4 & 1)], v);
            if (tid < 16) {
                float v2 = 0.f;
                #pragma unroll
                for (int q = 0; q < 16; ++q) v2 += sredO[tid][q];
                astoref(&spart[((size_t)0 * B + bq0 + tid) * 64 + dt], v2);
            }
            asm volatile("s_waitcnt vmcnt(0)" ::: "memory");
            if (tid == 0) astoreu(&stepflags[dt], 1u);   // step 0 done
        }
    }

    // ---- steps 1..9: per-wave eighth-granular flag wait ----
    for (int t = 1; t < C; ++t) {
        flag_wait(&stepflags[w * 8], 8, (unsigned)t, l);
        {
            union { u64 q; float f[2]; } sv;
            sv.q = aload64(&((u64*)spart)[((size_t)(t - 1) * B + b) * 32 + c8]);
            sredS2[lb][c8] = sv.f[0] + sv.f[1];
        }
        u64* Ain = (t & 1) ? hpA : hpB;
        u64* Aout = (t & 1) ? hpB : hpA;
        f4v acc[3];
        #pragma unroll
        for (int g = 0; g < 3; ++g) acc[g] = (f4v){0.f, 0.f, 0.f, 0.f};
        #pragma unroll
        for (int s8 = 0; s8 < 4; ++s8) {
            int s = w * 4 + s8;
            size_t base = (((size_t)bh * 32 + s) * 64 + l) * 2;
            union { u64 q[2]; s8v v; } au;
            au.q[0] = aload64(&Ain[base]);
            au.q[1] = aload64(&Ain[base + 1]);
            #pragma unroll
            for (int g = 0; g < 3; ++g)
                acc[g] = __builtin_amdgcn_mfma_f32_16x16x32_bf16(au.v, Bw[s8][g], acc[g], 0, 0, 0);
        }
        #pragma unroll
        for (int g = 0; g < 3; ++g)
            #pragma unroll
            for (int r = 0; r < 4; ++r)
                psum[w][(l >> 4) * 4 + r][g * 16 + (l & 15)] = acc[g][r];
        __syncthreads();
        if (epi) {
            float g3[3];
            #pragma unroll
            for (int g = 0; g < 3; ++g) {
                float v = 0.f;
                #pragma unroll
                for (int ww = 0; ww < 8; ++ww) v += psum[ww][lb][g * 16 + c];
                g3[g] = v;
            }
            float ssum = e_bo;
            #pragma unroll
            for (int q = 0; q < 32; ++q) ssum += sredS2[lb][q];
            float score = sigm(ssum);
            if (dt == 0 && c == 0) out[b * C + (t - 1)] = score;
            float gir = gilds[lb][c]      + score * e_w0;
            float giz = gilds[lb][16 + c] + score * e_w1;
            float gin = gilds[lb][32 + c] + score * e_w2;
            float rr = sigm(gir + e_b0 + g3[0]);
            float zz = sigm(giz + e_b1 + g3[1]);
            float nn = tanhf(gin + rr * (e_b2 + g3[2]));
            float hnew = (1.f - zz) * nn + zz * hl[lb][c];
            hl[lb][c] = hnew;
            hbf[lb][c] = (unsigned short)f2bf(hnew);
            sredO[lb][c] = hnew * e_wo;
        }
        __syncthreads();
        if (tid < 64) {  // wave 0 only: stores + drain + flag
            int lb2 = tid & 15, k4 = tid >> 4;
            u64 v = (u64)hbf[lb2][k4 * 4] | ((u64)hbf[lb2][k4 * 4 + 1] << 16) |
                    ((u64)hbf[lb2][k4 * 4 + 2] << 32) | ((u64)hbf[lb2][k4 * 4 + 3] << 48);
            int q2 = (2 * dt + (k4 >> 1)) & 3;
            int lane2 = lb2 + (q2 << 4);
            astore64(&Aout[(((size_t)bh * 32 + (dt >> 1)) * 64 + lane2) * 2 + (k4 & 1)], v);
            if (tid < 16) {
                float v2 = 0.f;
                #pragma unroll
                for (int q = 0; q < 16; ++q) v2 += sredO[tid][q];
                astoref(&spart[((size_t)t * B + bq0 + tid) * 64 + dt], v2);
            }
            asm volatile("s_waitcnt vmcnt(0)" ::: "memory");
            if (tid == 0) astoreu(&stepflags[dt], (unsigned)(t + 1));
        }
    }

    // ---- final: out[:, C-1] by dt==0 blocks (wait all 64 flags == C) ----
    if (dt == 0) {
        if (w == 0) flag_wait(stepflags, 64, (unsigned)C, l);
        __syncthreads();
        if (tid < 16) {
            int bb = bq0 + tid;
            float s = e_bo;
            for (int k = 0; k < 64; ++k) {
                float pv = __hip_atomic_load(&spart[((size_t)(C - 1) * B + bb) * 64 + k],
                                             __ATOMIC_RELAXED, __HIP_MEMORY_SCOPE_AGENT);
                s += pv;
            }
            out[bb * C + (C - 1)] = sigm(s);
        }
    }
}

extern "C" void kernel_launch(void* const* d_in, const int* in_sizes, int n_in,
                              void* d_out, int out_size, void* d_ws, size_t ws_size,
                              hipStream_t stream) {
    const float* feat  = (const float*)d_in[0];
    const float* a_w   = (const float*)d_in[1];
    const float* W_ih  = (const float*)d_in[2];
    const float* W_hh  = (const float*)d_in[3];
    const float* b_ih  = (const float*)d_in[4];
    const float* b_hh  = (const float*)d_in[5];
    const float* W_out = (const float*)d_in[6];
    const float* b_out = (const float*)d_in[7];
    float* out = (float*)d_out;
    float* ws = (float*)d_ws;

    float* part    = ws;                           // B*16*D f
    float* ml      = part + (size_t)B * 16 * D;    // B*16*2 f
    float* spart   = ml + B * 16 * 2;              // C*B*64 f
    float* wscore  = spart + (size_t)C * B * 64;   // TD f
    short* pooledP = (short*)(wscore + TD);        // B*D sh
    short* hpA     = pooledP + (size_t)B * D;      // B*D sh
    short* hpB     = hpA + (size_t)B * D;          // B*D sh
    short* BihP    = hpB + (size_t)B * D;          // D*TD sh
    short* BhhP    = BihP + (size_t)D * TD;        // D*TD sh
    unsigned* bar  = (unsigned*)(BhhP + (size_t)D * TD);  // 320 u32

    k_pre<<<dim3(4108), 256, 0, stream>>>(feat, a_w, W_ih, W_hh, part, ml,
                                          BihP, BhhP, wscore, bar);
    k_persist<<<dim3(256), 512, 0, stream>>>((const s8v*)BihP, (const s8v*)BhhP,
                                             pooledP, (u64*)hpA, (u64*)hpB,
                                             wscore, b_ih, b_hh, W_out, b_out,
                                             part, ml, spart, out, bar);
}

// Round 13
// 112.487 us; speedup vs baseline: 1308.2845x; 1.0020x over previous
//
#include <hip/hip_runtime.h>
#include <hip/hip_bf16.h>
#include <math.h>

#define B 64
#define S 1024
#define D 1024
#define C 10
#define TD 3072  // 3*D

typedef __attribute__((ext_vector_type(8))) short s8v;   // 8 bf16 (A/B frag)
typedef __attribute__((ext_vector_type(4))) float f4v;   // 4 f32  (C/D frag)
typedef unsigned long long u64;

__device__ __forceinline__ float wave_sum_bc(float v) {
    #pragma unroll
    for (int off = 1; off < 64; off <<= 1) v += __shfl_xor(v, off, 64);
    return v;
}
__device__ __forceinline__ float sigm(float x) { return 1.0f / (1.0f + expf(-x)); }
__device__ __forceinline__ short f2bf(float f) {
    __hip_bfloat16 h = __float2bfloat16(f);
    return *reinterpret_cast<short*>(&h);
}
// Agent-scope relaxed atomics: routed to L3, immune to stale per-XCD L2.
__device__ __forceinline__ u64 aload64(u64* p) {
    return __hip_atomic_load(p, __ATOMIC_RELAXED, __HIP_MEMORY_SCOPE_AGENT);
}
__device__ __forceinline__ void astore64(u64* p, u64 v) {
    __hip_atomic_store(p, v, __ATOMIC_RELAXED, __HIP_MEMORY_SCOPE_AGENT);
}
__device__ __forceinline__ void astoref(float* p, float v) {
    __hip_atomic_store(p, v, __ATOMIC_RELAXED, __HIP_MEMORY_SCOPE_AGENT);
}
// Per-wave poll: lane 0 spins; compiler fence stops hoisting of later loads.
__device__ __forceinline__ void wave_poll(unsigned* cnt, unsigned tgt, int l) {
    if (l == 0) {
        while (__hip_atomic_load(cnt, __ATOMIC_RELAXED, __HIP_MEMORY_SCOPE_AGENT) < tgt)
            __builtin_amdgcn_s_sleep(1);
    }
    asm volatile("" ::: "memory");
}

// ---------------------------------------------------------------------------
// k_pre: merged prologue (pooling partials + W packs + wscore + bar zero).
__global__ __launch_bounds__(256) void k_pre(const float* __restrict__ feat,
        const float* __restrict__ a_w, const float* __restrict__ W_ih,
        const float* __restrict__ W_hh, float* __restrict__ part, float* __restrict__ ml,
        short* __restrict__ BihP, short* __restrict__ BhhP, float* __restrict__ wscore,
        unsigned* __restrict__ bar) {
    __shared__ float sacc[4][1024];
    __shared__ float sml[4][2];
    int n = blockIdx.x, tid = threadIdx.x;

    if (n >= 1024) {
        if (n < 4096) {  // pack W
            int rel = n - 1024;
            const float* Wsrc = (rel < 1536) ? W_ih : W_hh;
            short* dst = (rel < 1536) ? BihP : BhhP;
            int stride = (rel < 1536) ? (D + 1) : D;
            int rn = (rel < 1536) ? rel : rel - 1536;
            int gid = rn * 256 + tid;
            int fid = gid >> 6, l = gid & 63;
            int s = fid & 31, g = (fid >> 5) % 3, dt = fid / 96;
            int row = g * 1024 + dt * 16 + (l & 15);
            int k0 = s * 32 + ((l >> 4) << 3);
            const float* src = Wsrc + (size_t)row * stride + k0;
            short v[8];
            #pragma unroll
            for (int j = 0; j < 8; ++j) v[j] = f2bf(src[j]);
            short* d = dst + ((size_t)fid * 64 + l) * 8;
            #pragma unroll
            for (int j = 0; j < 8; ++j) d[j] = v[j];
        } else {  // wscore + barrier zero
            int j = (n - 4096) * 256 + tid;
            wscore[j] = W_ih[(size_t)j * (D + 1) + D];
            if (n == 4096) {
                #pragma unroll
                for (int q = 0; q < 5; ++q) bar[q * 256 + tid] = 0u;
            }
        }
        return;
    }

    int ch = n & 15, b = n >> 4;
    int w = tid >> 6, lane = tid & 63;
    float4 aw[4], acc[4];
    #pragma unroll
    for (int r = 0; r < 4; ++r) {
        aw[r] = *reinterpret_cast<const float4*>(&a_w[r * 256 + lane * 4]);
        acc[r] = make_float4(0.f, 0.f, 0.f, 0.f);
    }
    float m = -INFINITY, l = 0.f;
    const float* fb = feat + ((size_t)b * S + ch * 64 + w * 16) * D;
    for (int i = 0; i < 16; ++i) {
        float4 f[4];
        #pragma unroll
        for (int r = 0; r < 4; ++r)
            f[r] = *reinterpret_cast<const float4*>(&fb[(size_t)i * D + r * 256 + lane * 4]);
        float dot = 0.f;
        #pragma unroll
        for (int r = 0; r < 4; ++r)
            dot += f[r].x * aw[r].x + f[r].y * aw[r].y + f[r].z * aw[r].z + f[r].w * aw[r].w;
        dot = wave_sum_bc(dot);
        if (dot <= m) {
            float wg = expf(dot - m);
            l += wg;
            #pragma unroll
            for (int r = 0; r < 4; ++r) {
                acc[r].x += wg * f[r].x; acc[r].y += wg * f[r].y;
                acc[r].z += wg * f[r].z; acc[r].w += wg * f[r].w;
            }
        } else {
            float sc = expf(m - dot);
            l = l * sc + 1.f;
            #pragma unroll
            for (int r = 0; r < 4; ++r) {
                acc[r].x = acc[r].x * sc + f[r].x; acc[r].y = acc[r].y * sc + f[r].y;
                acc[r].z = acc[r].z * sc + f[r].z; acc[r].w = acc[r].w * sc + f[r].w;
            }
            m = dot;
        }
    }
    #pragma unroll
    for (int r = 0; r < 4; ++r)
        *reinterpret_cast<float4*>(&sacc[w][r * 256 + lane * 4]) = acc[r];
    if (lane == 0) { sml[w][0] = m; sml[w][1] = l; }
    __syncthreads();
    float m0 = sml[0][0], m1 = sml[1][0], m2 = sml[2][0], m3 = sml[3][0];
    float mg = fmaxf(fmaxf(m0, m1), fmaxf(m2, m3));
    float s0 = expf(m0 - mg), s1 = expf(m1 - mg), s2 = expf(m2 - mg), s3 = expf(m3 - mg);
    int c = tid * 4;
    float4 a0 = *reinterpret_cast<float4*>(&sacc[0][c]);
    float4 a1 = *reinterpret_cast<float4*>(&sacc[1][c]);
    float4 a2 = *reinterpret_cast<float4*>(&sacc[2][c]);
    float4 a3 = *reinterpret_cast<float4*>(&sacc[3][c]);
    float4 o;
    o.x = s0 * a0.x + s1 * a1.x + s2 * a2.x + s3 * a3.x;
    o.y = s0 * a0.y + s1 * a1.y + s2 * a2.y + s3 * a3.y;
    o.z = s0 * a0.z + s1 * a1.z + s2 * a2.z + s3 * a3.z;
    o.w = s0 * a0.w + s1 * a1.w + s2 * a2.w + s3 * a3.w;
    *reinterpret_cast<float4*>(&part[((size_t)b * 16 + ch) * D + c]) = o;
    if (tid == 0) {
        float lg = s0 * sml[0][1] + s1 * sml[1][1] + s2 * sml[2][1] + s3 * sml[3][1];
        ml[(b * 16 + ch) * 2] = mg;
        ml[(b * 16 + ch) * 2 + 1] = lg;
    }
}

// ---------------------------------------------------------------------------
// k_persist: pool-combine + step0 + 9 GRU steps + final.
// Grid 256 = (dt 0..63)x(bh 0..3) XCD-pinned, block 512 = 8 waves (k-eighths).
// Per-eighth counters: wave w waits only for the 8 producer blocks of its
// k-range. Cross-block data via agent-scope relaxed atomics (L3-coherent).
__global__ __launch_bounds__(512, 2) void k_persist(const s8v* __restrict__ BihP,
        const s8v* __restrict__ BhhP, short* pooledP,
        u64* hpA, u64* hpB, const float* __restrict__ wscore,
        const float* __restrict__ b_ih, const float* __restrict__ b_hh,
        const float* __restrict__ W_out, const float* __restrict__ b_out,
        const float* __restrict__ part, const float* __restrict__ ml,
        float* spart, float* __restrict__ out, unsigned* bar) {
    __shared__ float psum[8][16][49];
    __shared__ float gilds[16][49];
    __shared__ float hl[16][17];
    __shared__ float sredS2[16][33];
    __shared__ float sredO[16][17];
    __shared__ unsigned short hbf[16][16];

    int tid = threadIdx.x, w = tid >> 6, l = tid & 63;
    int n = blockIdx.x, xcd = n & 7, slot = n >> 3;
    int dt = xcd * 8 + (slot & 7), bh = slot >> 3;
    int bq0 = bh * 16;
    int lb = tid & 15, c = (tid >> 4) & 15, c8 = tid >> 4;  // c8 0..31
    bool epi = (tid < 256);
    int b = bq0 + lb, d = dt * 16 + c;
    unsigned* cnt8 = &bar[(bh * 8) * 32];        // cnt8[e] at bar[(bh*8+e)*32]
    unsigned* cnt_pool = &bar[1024];
    u64* poolU = (u64*)pooledP;

    // ---- Phase A: pool-combine (blocks 0..63), u64 agent stores ----
    if (n < 64 && tid < 256) {
        int bb = n;
        float mg = -INFINITY;
        #pragma unroll
        for (int q = 0; q < 16; ++q) mg = fmaxf(mg, ml[(bb * 16 + q) * 2]);
        float denom = 0.f, sc[16];
        #pragma unroll
        for (int q = 0; q < 16; ++q) {
            sc[q] = expf(ml[(bb * 16 + q) * 2] - mg);
            denom += sc[q] * ml[(bb * 16 + q) * 2 + 1];
        }
        float inv = 1.f / denom;
        int cc = tid * 4;
        float4 o = make_float4(0.f, 0.f, 0.f, 0.f);
        #pragma unroll
        for (int q = 0; q < 16; ++q) {
            float4 p = *reinterpret_cast<const float4*>(&part[((size_t)bb * 16 + q) * D + cc]);
            o.x += sc[q] * p.x; o.y += sc[q] * p.y; o.z += sc[q] * p.z; o.w += sc[q] * p.w;
        }
        u64 v = (u64)(unsigned short)f2bf(o.x * inv) |
                ((u64)(unsigned short)f2bf(o.y * inv) << 16) |
                ((u64)(unsigned short)f2bf(o.z * inv) << 32) |
                ((u64)(unsigned short)f2bf(o.w * inv) << 48);
        int lane2 = (bb & 15) + (((cc >> 3) & 3) << 4);
        size_t idx = (((size_t)(bb >> 4) * 32 + (cc >> 5)) * 64 + lane2) * 2 + ((cc >> 2) & 1);
        astore64(&poolU[idx], v);
    }
    if (n < 64) {
        __syncthreads();  // drain combine stores (vmcnt) for all waves
        if (tid == 0) {
            asm volatile("s_waitcnt vmcnt(0)" ::: "memory");
            __hip_atomic_fetch_add(cnt_pool, 1u, __ATOMIC_RELAXED, __HIP_MEMORY_SCOPE_AGENT);
        }
    }

    // ---- Preload constants + W_hh fragments (overlaps pool wait) ----
    float e_bo = b_out[0];
    float e_b0 = 0.f, e_b1 = 0.f, e_b2 = 0.f, e_wo = 0.f;
    float e_w0 = 0.f, e_w1 = 0.f, e_w2 = 0.f, e_i0 = 0.f, e_i1 = 0.f, e_i2 = 0.f;
    if (epi) {
        e_b0 = b_hh[d]; e_b1 = b_hh[D + d]; e_b2 = b_hh[2 * D + d];
        e_wo = W_out[d];
        e_w0 = wscore[d]; e_w1 = wscore[D + d]; e_w2 = wscore[2 * D + d];
        e_i0 = b_ih[d]; e_i1 = b_ih[D + d]; e_i2 = b_ih[2 * D + d];
    }
    s8v Bw[4][3];
    #pragma unroll
    for (int s8 = 0; s8 < 4; ++s8) {
        int s = w * 4 + s8;
        #pragma unroll
        for (int g = 0; g < 3; ++g)
            Bw[s8][g] = BhhP[((size_t)(dt * 3 + g) * 32 + s) * 64 + l];
    }

    // ---- wait for pooled ----
    if (tid == 0) {
        while (__hip_atomic_load(cnt_pool, __ATOMIC_RELAXED, __HIP_MEMORY_SCOPE_AGENT) < 64u)
            __builtin_amdgcn_s_sleep(1);
    }
    __syncthreads();

    // ---- step 0: A = pooledP (aload64), B = W_ih ----
    {
        f4v acc[3];
        #pragma unroll
        for (int g = 0; g < 3; ++g) acc[g] = (f4v){0.f, 0.f, 0.f, 0.f};
        #pragma unroll
        for (int s8 = 0; s8 < 4; ++s8) {
            int s = w * 4 + s8;
            size_t base = (((size_t)bh * 32 + s) * 64 + l) * 2;
            union { u64 q[2]; s8v v; } au;
            au.q[0] = aload64(&poolU[base]);
            au.q[1] = aload64(&poolU[base + 1]);
            #pragma unroll
            for (int g = 0; g < 3; ++g) {
                s8v bb2 = BihP[((size_t)(dt * 3 + g) * 32 + s) * 64 + l];
                acc[g] = __builtin_amdgcn_mfma_f32_16x16x32_bf16(au.v, bb2, acc[g], 0, 0, 0);
            }
        }
        #pragma unroll
        for (int g = 0; g < 3; ++g)
            #pragma unroll
            for (int r = 0; r < 4; ++r)
                psum[w][(l >> 4) * 4 + r][g * 16 + (l & 15)] = acc[g][r];
        __syncthreads();
        if (epi) {
            float g3[3];
            #pragma unroll
            for (int g = 0; g < 3; ++g) {
                float v = 0.f;
                #pragma unroll
                for (int ww = 0; ww < 8; ++ww) v += psum[ww][lb][g * 16 + c];
                g3[g] = v;
            }
            float gir = g3[0] + e_i0, giz = g3[1] + e_i1, gin = g3[2] + e_i2;
            gilds[lb][c] = gir; gilds[lb][16 + c] = giz; gilds[lb][32 + c] = gin;
            float rr = sigm(gir + e_b0);
            float zz = sigm(giz + e_b1);
            float nn = tanhf(gin + rr * e_b2);
            float hnew = (1.f - zz) * nn;  // hprev = 0
            hl[lb][c] = hnew;
            hbf[lb][c] = (unsigned short)f2bf(hnew);
            sredO[lb][c] = hnew * e_wo;
        }
        __syncthreads();
        if (tid < 64) {
            int lb2 = tid & 15, k4 = tid >> 4;
            u64 v = (u64)hbf[lb2][k4 * 4] | ((u64)hbf[lb2][k4 * 4 + 1] << 16) |
                    ((u64)hbf[lb2][k4 * 4 + 2] << 32) | ((u64)hbf[lb2][k4 * 4 + 3] << 48);
            int q2 = (2 * dt + (k4 >> 1)) & 3;
            int lane2 = lb2 + (q2 << 4);
            astore64(&hpA[(((size_t)bh * 32 + (dt >> 1)) * 64 + lane2) * 2 + (k4 & 1)], v);
            if (tid < 16) {
                float v2 = 0.f;
                #pragma unroll
                for (int q = 0; q < 16; ++q) v2 += sredO[tid][q];
                astoref(&spart[((size_t)0 * B + bq0 + tid) * 64 + dt], v2);
            }
            asm volatile("s_waitcnt vmcnt(0)" ::: "memory");
            if (tid == 0)
                __hip_atomic_fetch_add(&cnt8[(dt >> 3) * 32], 1u, __ATOMIC_RELAXED,
                                       __HIP_MEMORY_SCOPE_AGENT);
        }
    }

    // ---- steps 1..9: per-wave eighth-granular barrier ----
    for (int t = 1; t < C; ++t) {
        wave_poll(&cnt8[w * 32], (unsigned)(t * 8), l);
        // spart pair for this wave's dt-eighth (c8*2, c8*2+1)
        {
            union { u64 q; float f[2]; } sv;
            sv.q = aload64(&((u64*)spart)[((size_t)(t - 1) * B + b) * 32 + c8]);
            sredS2[lb][c8] = sv.f[0] + sv.f[1];
        }
        u64* Ain = (t & 1) ? hpA : hpB;
        u64* Aout = (t & 1) ? hpB : hpA;
        f4v acc[3];
        #pragma unroll
        for (int g = 0; g < 3; ++g) acc[g] = (f4v){0.f, 0.f, 0.f, 0.f};
        #pragma unroll
        for (int s8 = 0; s8 < 4; ++s8) {
            int s = w * 4 + s8;
            size_t base = (((size_t)bh * 32 + s) * 64 + l) * 2;
            union { u64 q[2]; s8v v; } au;
            au.q[0] = aload64(&Ain[base]);
            au.q[1] = aload64(&Ain[base + 1]);
            #pragma unroll
            for (int g = 0; g < 3; ++g)
                acc[g] = __builtin_amdgcn_mfma_f32_16x16x32_bf16(au.v, Bw[s8][g], acc[g], 0, 0, 0);
        }
        #pragma unroll
        for (int g = 0; g < 3; ++g)
            #pragma unroll
            for (int r = 0; r < 4; ++r)
                psum[w][(l >> 4) * 4 + r][g * 16 + (l & 15)] = acc[g][r];
        __syncthreads();
        if (epi) {
            float g3[3];
            #pragma unroll
            for (int g = 0; g < 3; ++g) {
                float v = 0.f;
                #pragma unroll
                for (int ww = 0; ww < 8; ++ww) v += psum[ww][lb][g * 16 + c];
                g3[g] = v;
            }
            float ssum = e_bo;
            #pragma unroll
            for (int q = 0; q < 32; ++q) ssum += sredS2[lb][q];
            float score = sigm(ssum);
            if (dt == 0 && c == 0) out[b * C + (t - 1)] = score;
            float gir = gilds[lb][c]      + score * e_w0;
            float giz = gilds[lb][16 + c] + score * e_w1;
            float gin = gilds[lb][32 + c] + score * e_w2;
            float rr = sigm(gir + e_b0 + g3[0]);
            float zz = sigm(giz + e_b1 + g3[1]);
            float nn = tanhf(gin + rr * (e_b2 + g3[2]));
            float hnew = (1.f - zz) * nn + zz * hl[lb][c];
            hl[lb][c] = hnew;
            hbf[lb][c] = (unsigned short)f2bf(hnew);
            sredO[lb][c] = hnew * e_wo;
        }
        __syncthreads();
        if (tid < 64) {  // wave 0 only: stores + drain + arrival
            int lb2 = tid & 15, k4 = tid >> 4;
            u64 v = (u64)hbf[lb2][k4 * 4] | ((u64)hbf[lb2][k4 * 4 + 1] << 16) |
                    ((u64)hbf[lb2][k4 * 4 + 2] << 32) | ((u64)hbf[lb2][k4 * 4 + 3] << 48);
            int q2 = (2 * dt + (k4 >> 1)) & 3;
            int lane2 = lb2 + (q2 << 4);
            astore64(&Aout[(((size_t)bh * 32 + (dt >> 1)) * 64 + lane2) * 2 + (k4 & 1)], v);
            if (tid < 16) {
                float v2 = 0.f;
                #pragma unroll
                for (int q = 0; q < 16; ++q) v2 += sredO[tid][q];
                astoref(&spart[((size_t)t * B + bq0 + tid) * 64 + dt], v2);
            }
            asm volatile("s_waitcnt vmcnt(0)" ::: "memory");
            if (tid == 0)
                __hip_atomic_fetch_add(&cnt8[(dt >> 3) * 32], 1u, __ATOMIC_RELAXED,
                                       __HIP_MEMORY_SCOPE_AGENT);
        }
    }

    // ---- final: out[:, C-1] by dt==0 blocks ----
    if (dt == 0) {
        if (tid == 0) {
            unsigned tgt = (unsigned)(C * 64);
            // wait for all 8 eighth-counters of this chain to reach C*8
            for (int e = 0; e < 8; ++e) {
                while (__hip_atomic_load(&cnt8[e * 32], __ATOMIC_RELAXED,
                                         __HIP_MEMORY_SCOPE_AGENT) < (unsigned)(C * 8))
                    __builtin_amdgcn_s_sleep(4);
            }
            (void)tgt;
        }
        __syncthreads();
        if (tid < 16) {
            int bb = bq0 + tid;
            float s = e_bo;
            for (int k = 0; k < 64; ++k) {
                float pv = __hip_atomic_load(&spart[((size_t)(C - 1) * B + bb) * 64 + k],
                                             __ATOMIC_RELAXED, __HIP_MEMORY_SCOPE_AGENT);
                s += pv;
            }
            out[bb * C + (C - 1)] = sigm(s);
        }
    }
}

extern "C" void kernel_launch(void* const* d_in, const int* in_sizes, int n_in,
                              void* d_out, int out_size, void* d_ws, size_t ws_size,
                              hipStream_t stream) {
    const float* feat  = (const float*)d_in[0];
    const float* a_w   = (const float*)d_in[1];
    const float* W_ih  = (const float*)d_in[2];
    const float* W_hh  = (const float*)d_in[3];
    const float* b_ih  = (const float*)d_in[4];
    const float* b_hh  = (const float*)d_in[5];
    const float* W_out = (const float*)d_in[6];
    const float* b_out = (const float*)d_in[7];
    float* out = (float*)d_out;
    float* ws = (float*)d_ws;

    float* part    = ws;                           // B*16*D f
    float* ml      = part + (size_t)B * 16 * D;    // B*16*2 f
    float* spart   = ml + B * 16 * 2;              // C*B*64 f
    float* wscore  = spart + (size_t)C * B * 64;   // TD f
    short* pooledP = (short*)(wscore + TD);        // B*D sh
    short* hpA     = pooledP + (size_t)B * D;      // B*D sh
    short* hpB     = hpA + (size_t)B * D;          // B*D sh
    short* BihP    = hpB + (size_t)B * D;          // D*TD sh
    short* BhhP    = BihP + (size_t)D * TD;        // D*TD sh
    unsigned* bar  = (unsigned*)(BhhP + (size_t)D * TD);  // 1280 u32

    k_pre<<<dim3(4108), 256, 0, stream>>>(feat, a_w, W_ih, W_hh, part, ml,
                                          BihP, BhhP, wscore, bar);
    k_persist<<<dim3(256), 512, 0, stream>>>((const s8v*)BihP, (const s8v*)BhhP,
                                             pooledP, (u64*)hpA, (u64*)hpB,
                                             wscore, b_ih, b_hh, W_out, b_out,
                                             part, ml, spart, out, bar);
}